// Round 13
// baseline (427.340 us; speedup 1.0000x reference)
//
#include <hip/hip_runtime.h>
#include <hip/hip_cooperative_groups.h>
#include <math.h>

namespace cg = cooperative_groups;

// CrowdDet RetinaNet loss constants
#define POS_T 0.5f
#define NEG_T 0.4f
#define F_ALPHA 0.25f
#define SL1_BETA 0.1f
#define SENT 3.0e8f

// Pruning geometry: 8x8 cells of 128px, 6 anchor-area classes (x2.5 steps).
// Only gts with iou >= 0.4 can affect the output; keep any gt passing a
// conservative necessary-condition test for iou >= 0.37 (margins >> f32 eps).
#define NCELL 8
#define NCLASS 6
#define NB (NCELL * NCELL * NCLASS)   // 384 buckets
#define KEEP_T 0.37f
#define APT 8                          // anchors per thread in phases A/C

// Anchor legacy-area class thresholds: 289 * 2.5^k (exact in f32).
__device__ __constant__ float AT[7] = {
    289.f, 722.5f, 1806.25f, 4515.625f, 11289.0625f, 28222.65625f, 70556.640625f};

__device__ __forceinline__ float smooth_l1(float d) {
    d = fabsf(d);
    return d < SL1_BETA ? 0.5f * d * d / SL1_BETA : d - SL1_BETA;
}

__device__ __forceinline__ int bucket_of(const float4 av) {
    const float aw = av.z - av.x + 1.f, ah = av.w - av.y + 1.f;
    const float Aa = aw * ah;
    const float cx = 0.5f * (av.x + av.z);
    const float cy = 0.5f * (av.y + av.w);
    const int cxi = min(NCELL - 1, max(0, (int)(cx * (1.0f / 128.f))));
    const int cyi = min(NCELL - 1, max(0, (int)(cy * (1.0f / 128.f))));
    const int k = (Aa > AT[1]) + (Aa > AT[2]) + (Aa > AT[3])
                + (Aa > AT[4]) + (Aa > AT[5]);
    return (k << 6) | (cyi << 3) | cxi;
}

// One cooperative kernel: A(prep+hist) -> B(scan+lists) -> C(place)
// -> D(loss, both batches per anchor) -> E(finalize). Phase bodies are
// verbatim from the validated R12 kernels.
__global__ __launch_bounds__(256, 4) void mega_kernel(
    const float* __restrict__ pred_cls, const float* __restrict__ pred_reg,
    const float* __restrict__ anchors, const float* __restrict__ gt,
    const float* __restrict__ im_info,
    float4* __restrict__ X4, float* __restrict__ AREA, float* __restrict__ Y,
    int* __restrict__ bucketid, int* __restrict__ blockhist,
    int* __restrict__ totals, int* __restrict__ cnt_arr, int* __restrict__ lists,
    int* __restrict__ sorted, int* __restrict__ sortedbkt,
    double* __restrict__ ws, float* __restrict__ out,
    int A, int G, int Gslots, int Gp, int B, int nablk, int ngtblk, int CH)
{
#pragma clang fp contract(off)
    cg::grid_group gg = cg::this_grid();
    __shared__ int lh[NB];
    __shared__ int sbase[NB];
    __shared__ int s[256];
    __shared__ float s_lc[4], s_lr[4];
    __shared__ int s_np[4];

    const int t = threadIdx.x;
    const int blk = blockIdx.x;

    // ================= Phase A: ws zero + gt prep + anchor hist =============
    if (blk == 0 && t < 34) ws[t] = 0.0;

    if (blk >= nablk && blk < nablk + ngtblk) {
        const int i = (blk - nablk) * 256 + t;
        if (i < B * Gslots) {
            const int b = i / Gslots, j = i - b * Gslots;
            const int nv = (int)im_info[b * 6 + 5];
            float g0, g1, g2, g3, cls, area;
            if (j < nv) {
                const float* sp = gt + ((size_t)b * G + j) * 5;
                g0 = sp[0]; g1 = sp[1]; g2 = sp[2]; g3 = sp[3]; cls = sp[4];
                area = (g2 - g0 + 1.f) * (g3 - g1 + 1.f);   // exact ref op order
            } else {
                // Sentinel far-away box: inter = 0 with any real anchor;
                // once a real gt is in (bi>=0), it can never win argmax.
                g0 = SENT; g1 = SENT; g2 = SENT + 1.f; g3 = SENT + 1.f;
                cls = 0.f; area = 4.f;
            }
            X4[i] = make_float4(g0, g1, g2 + 1.f, g3 + 1.f);  // pre-added +1
            AREA[i] = area;
            float* y = Y + (size_t)i * 8;
            reinterpret_cast<float4*>(y)[0] = make_float4(g0, g1, g2, g3);
            y[4] = cls;
        }
    }

    if (blk < nablk) {
        for (int i = t; i < NB; i += 256) lh[i] = 0;
        __syncthreads();
        const int abase = (blk * 256 + t) * APT;
        #pragma unroll
        for (int u = 0; u < APT; ++u) {
            const int ai = abase + u;
            if (ai < A) {
                const float4 av = *reinterpret_cast<const float4*>(anchors + 4 * (size_t)ai);
                const int bk = bucket_of(av);
                bucketid[ai] = bk;
                atomicAdd(&lh[bk], 1);    // LDS atomic: per-CU, cheap
            }
        }
        __syncthreads();
        for (int j = t; j < NB; j += 256)
            blockhist[(size_t)blk * NB + j] = lh[j];   // coalesced burst
    }
    gg.sync();

    // ================= Phase B: per-bucket scan + candidate lists ===========
    if (blk < NB) {
        const int bk = blk;
        const int v = (t < nablk) ? blockhist[(size_t)t * NB + bk] : 0;
        s[t] = v;
        __syncthreads();
        for (int d = 1; d < 256; d <<= 1) {
            const int u = (t >= d) ? s[t - d] : 0;
            __syncthreads();
            s[t] += u;
            __syncthreads();
        }
        if (t < nablk) blockhist[(size_t)t * NB + bk] = s[t] - v;  // exclusive
        if (t == 255) totals[bk] = s[255];

        const int wid = t >> 6, lane = t & 63;
        for (int b = wid; b < B; b += 4) {
            const int nv = __builtin_amdgcn_readfirstlane((int)im_info[b * 6 + 5]);
            const int cxi = bk & 7, cyi = (bk >> 3) & 7, k = bk >> 6;
            const float cx0 = cxi * 128.f, cx1 = cx0 + 128.f;
            const float cy0 = cyi * 128.f, cy1 = cy0 + 128.f;
            const float Alo = AT[k], Ahi = AT[k + 1];
            const float4* __restrict__ X4b = X4 + (size_t)b * Gslots;
            const float* __restrict__ Ab = AREA + (size_t)b * Gslots;
            int* __restrict__ list = lists + ((size_t)(b * NB + bk)) * Gp;

            int cnt = 0;
            for (int base = 0; base < nv; base += 64) {
                const int j = base + lane;
                bool keep = false;
                if (j < nv) {
                    const float4 q = X4b[j];          // {g0, g1, g2+1, g3+1}
                    const float ag = Ab[j];
                    const float wg = q.z - q.x;
                    const float hg = q.w - q.y;
                    const float ox = fminf(cx1 + 129.f, q.z) - fmaxf(cx0 - 128.f, q.x);
                    const float oy = fminf(cy1 + 129.f, q.w) - fmaxf(cy0 - 128.f, q.y);
                    keep = (ox >= KEEP_T * wg) && (oy >= KEEP_T * hg)
                        && (ag >= KEEP_T * Alo) && (KEEP_T * ag <= Ahi);
                }
                const unsigned long long m = __ballot(keep);
                if (keep) {
                    const int pos = cnt + __popcll(m & ((1ull << lane) - 1ull));
                    list[pos] = j;
                }
                cnt += __popcll(m);
            }
            if (lane == 0) cnt_arr[b * NB + bk] = cnt;
        }
    }
    gg.sync();

    // ================= Phase C: bases + place anchors =======================
    if (blk < nablk) {
        for (int i = t; i < NB; i += 256) lh[i] = 0;
        if (t < 64) {
            int carry = 0;
            #pragma unroll
            for (int r = 0; r < NB / 64; ++r) {
                int v = totals[r * 64 + t];
                const int orig = v;
                for (int d = 1; d < 64; d <<= 1) {
                    const int u = __shfl_up(v, d);
                    if (t >= d) v += u;
                }
                sbase[r * 64 + t] = carry + v - orig;   // exclusive
                carry += __shfl(v, 63);
            }
        }
        __syncthreads();
        const int abase = (blk * 256 + t) * APT;
        #pragma unroll
        for (int u = 0; u < APT; ++u) {
            const int ai = abase + u;
            if (ai < A) {
                const int bk = bucketid[ai];
                const int lrk = atomicAdd(&lh[bk], 1);
                const int slot = sbase[bk] + blockhist[(size_t)blk * NB + bk] + lrk;
                sorted[slot] = ai;
                sortedbkt[slot] = bk;
            }
        }
    }
    gg.sync();

    // ================= Phase D: main loss (both batches per anchor) =========
    if (blk < CH) {
        const int i_raw = blk * 256 + t;
        const bool live = i_raw < A;
        const int i = min(i_raw, A - 1);
        const int a = sorted[i];
        const int bk = sortedbkt[i];

        const float4 anc = *reinterpret_cast<const float4*>(anchors + 4 * (size_t)a);
        const float a0 = anc.x, a1 = anc.y;
        const float aw = anc.z - anc.x + 1.f;
        const float ah = anc.w - anc.y + 1.f;
        const float area_a = aw * ah;
        const float a2p = anc.z + 1.f;    // +1 pre-added (commutes with min)
        const float a3p = anc.w + 1.f;

        float lc = 0.f, lr = 0.f;
        int fg = 0;

        for (int b = 0; b < B; ++b) {
            const int cnt = cnt_arr[b * NB + bk];
            const int* __restrict__ ids = lists + ((size_t)(b * NB + bk)) * Gp;
            const float4* __restrict__ X4b = X4 + (size_t)b * Gslots;
            const float* __restrict__ Ab = AREA + (size_t)b * Gslots;
            const float* __restrict__ Yb = Y + (size_t)b * Gslots * 8;

            // Division-free IoU argmax over candidates (ascending gt index ->
            // first-max preserved; pruned gts provably < 0.37 iou can't matter).
            float bi = -1.f, bS = 1.f;
            int arg = 0;
            for (int g = 0; g < cnt; ++g) {
                const int idx = ids[g];
                const float4 q = X4b[idx];
                const float sg = Ab[idx];
                const float iw = fminf(a2p, q.z) - fmaxf(a0, q.x);
                const float ih = fminf(a3p, q.w) - fmaxf(a1, q.y);
                const float inter = fmaxf(iw, 0.f) * fmaxf(ih, 0.f);
                const float S = area_a + sg;
                const bool upd = inter * bS > bi * S;
                bi  = upd ? inter : bi;
                bS  = upd ? S     : bS;
                arg = upd ? idx   : arg;
            }

            if (live) {
                // ONE division, exact ref expr: inter/((area_a+area_g)-inter)
                const float max_ov = bi / (bS - bi);

                float label = 0.f;
                bool valid = true;
                if (max_ov >= POS_T) {
                    label = Yb[(size_t)arg * 8 + 4];
                } else if (max_ov >= NEG_T) {
                    valid = false;                 // ignore band
                }
                const int f = (label > 0.f) ? 1 : 0;
                fg += f;

                if (valid) {
                    const float x = pred_cls[(size_t)b * A + a];
                    const float p = 1.f / (1.f + expf(-x));
                    const float l1p = log1pf(expf(-fabsf(x)));
                    const float log_p  = fminf(x, 0.f) - l1p;    // log_sigmoid(x)
                    const float log_np = fminf(-x, 0.f) - l1p;   // log_sigmoid(-x)
                    const float pos = (label == 1.f) ? 1.f : 0.f;
                    const float omp = 1.f - p;
                    lc += -(F_ALPHA * pos * (omp * omp) * log_p
                            + (1.f - F_ALPHA) * (1.f - pos) * (p * p) * log_np);
                }

                if (f) {
                    const float4 gb = *reinterpret_cast<const float4*>(Yb + (size_t)arg * 8);
                    const float gw = gb.z - gb.x + 1.f;
                    const float gh = gb.w - gb.y + 1.f;
                    const float gx = gb.x + 0.5f * gw;
                    const float gy = gb.y + 0.5f * gh;
                    const float axc = a0 + 0.5f * aw;
                    const float ayc = a1 + 0.5f * ah;
                    const float t0 = (gx - axc) / aw;
                    const float t1 = (gy - ayc) / ah;
                    const float t2 = logf(gw / aw);
                    const float t3 = logf(gh / ah);
                    const float4 rr = *reinterpret_cast<const float4*>(
                        pred_reg + 4 * ((size_t)b * A + a));
                    lr += smooth_l1(rr.x - t0) + smooth_l1(rr.y - t1)
                        + smooth_l1(rr.z - t2) + smooth_l1(rr.w - t3);
                }
            }
        }

        // wave64 reduction
        for (int off = 32; off > 0; off >>= 1) {
            lc += __shfl_down(lc, off);
            lr += __shfl_down(lr, off);
            fg += __shfl_down(fg, off);
        }
        const int wid = t >> 6;
        const int lane = t & 63;
        if (lane == 0) { s_lc[wid] = lc; s_lr[wid] = lr; s_np[wid] = fg; }
        __syncthreads();
        if (t == 0) {
            const float tlc = s_lc[0] + s_lc[1] + s_lc[2] + s_lc[3];
            const float tlr = s_lr[0] + s_lr[1] + s_lr[2] + s_lr[3];
            const int   tnp = s_np[0] + s_np[1] + s_np[2] + s_np[3];
            __hip_atomic_fetch_add(&ws[0],  (double)tlc, __ATOMIC_RELAXED, __HIP_MEMORY_SCOPE_AGENT);
            __hip_atomic_fetch_add(&ws[16], (double)tlr, __ATOMIC_RELAXED, __HIP_MEMORY_SCOPE_AGENT);
            __hip_atomic_fetch_add(&ws[32], (double)tnp, __ATOMIC_RELAXED, __HIP_MEMORY_SCOPE_AGENT);
        }
    }
    gg.sync();

    // ================= Phase E: finalize ====================================
    if (blk == 0 && t == 0) {
        const double npos = ws[32] < 1.0 ? 1.0 : ws[32];
        const double norm = 0.9 * 100.0 + 0.1 * npos;
        out[0] = (float)(ws[0] / norm);
        out[1] = (float)(ws[16] / norm);
    }
}

extern "C" void kernel_launch(void* const* d_in, const int* in_sizes, int n_in,
                              void* d_out, int out_size, void* d_ws, size_t ws_size,
                              hipStream_t stream) {
    const float* pred_cls = (const float*)d_in[0];
    const float* pred_reg = (const float*)d_in[1];
    const float* anchors  = (const float*)d_in[2];
    const float* gt_boxes = (const float*)d_in[3];
    const float* im_info  = (const float*)d_in[4];

    int A = in_sizes[2] / 4;
    int B = in_sizes[4] / 6;
    int G = in_sizes[3] / (B * 5);
    int Gp = (G + 63) & ~63;
    int Gslots = Gp + 64;
    int nablk = ((A + APT - 1) / APT + 255) / 256;      // anchor-hist blocks (<=256)
    int ngtblk = (B * Gslots + 255) / 256;              // gt-prep blocks
    int CH = (A + 255) / 256;                           // loss chunks

    int NGRID = CH;
    if (NGRID < NB) NGRID = NB;
    if (NGRID < nablk + ngtblk) NGRID = nablk + ngtblk;
    // __launch_bounds__(256,4) guarantees >=4 blocks/CU -> 1024 co-resident;
    // NGRID = 782 for the bench shape, well under.

    // ---- ws layout ----
    char* base = (char*)d_ws;
    double* ws = (double*)base;                  // [0,512): accumulators
    size_t off = 512;
    float4* X4 = (float4*)(base + off);     off += (size_t)B * Gslots * 16;
    float* AREA = (float*)(base + off);     off += (size_t)B * Gslots * 4;
    float* Y = (float*)(base + off);        off += (size_t)B * Gslots * 32;
    off = (off + 255) & ~(size_t)255;
    int* cnt_arr = (int*)(base + off);      off += (size_t)B * NB * 4;
    int* lists = (int*)(base + off);        off += (size_t)B * NB * Gp * 4;
    off = (off + 255) & ~(size_t)255;
    int* bucketid = (int*)(base + off);     off += (size_t)A * 4;
    int* sorted = (int*)(base + off);       off += (size_t)A * 4;
    int* sortedbkt = (int*)(base + off);    off += (size_t)A * 4;
    off = (off + 255) & ~(size_t)255;
    int* blockhist = (int*)(base + off);    off += (size_t)nablk * NB * 4;
    int* totals = (int*)(base + off);       off += (size_t)NB * 4;

    float* out = (float*)d_out;

    void* args[] = {
        (void*)&pred_cls, (void*)&pred_reg, (void*)&anchors, (void*)&gt_boxes,
        (void*)&im_info, (void*)&X4, (void*)&AREA, (void*)&Y,
        (void*)&bucketid, (void*)&blockhist, (void*)&totals,
        (void*)&cnt_arr, (void*)&lists, (void*)&sorted, (void*)&sortedbkt,
        (void*)&ws, (void*)&out,
        (void*)&A, (void*)&G, (void*)&Gslots, (void*)&Gp, (void*)&B,
        (void*)&nablk, (void*)&ngtblk, (void*)&CH};

    hipLaunchCooperativeKernel((void*)mega_kernel, dim3(NGRID), dim3(256),
                               args, 0, stream);
}

// Round 14
// 92.102 us; speedup vs baseline: 4.6399x; 4.6399x over previous
//
#include <hip/hip_runtime.h>
#include <math.h>

// CrowdDet RetinaNet loss constants
#define POS_T 0.5f
#define NEG_T 0.4f
#define F_ALPHA 0.25f
#define SL1_BETA 0.1f

// Pruning geometry: 8x8 cells of 128px, 6 anchor-area classes (x2.5 steps).
// Only gts with iou >= 0.4 can affect the output; keep any gt passing a
// conservative necessary-condition test for iou >= 0.37 (validated R10-R12).
#define NCELL 8
#define NCLASS 6
#define NB (NCELL * NCELL * NCLASS)   // 384 buckets
#define KEEP_T 0.37f

// Anchor legacy-area class thresholds: 289 * 2.5^k (exact in f32).
__device__ __constant__ float AT[7] = {
    289.f, 722.5f, 1806.25f, 4515.625f, 11289.0625f, 28222.65625f, 70556.640625f};

__device__ __forceinline__ float smooth_l1(float d) {
    d = fabsf(d);
    return d < SL1_BETA ? 0.5f * d * d / SL1_BETA : d - SL1_BETA;
}

__device__ __forceinline__ int bucket_of(const float4 av) {
    const float aw = av.z - av.x + 1.f, ah = av.w - av.y + 1.f;
    const float Aa = aw * ah;
    const float cx = 0.5f * (av.x + av.z);
    const float cy = 0.5f * (av.y + av.w);
    const int cxi = min(NCELL - 1, max(0, (int)(cx * (1.0f / 128.f))));
    const int cyi = min(NCELL - 1, max(0, (int)(cy * (1.0f / 128.f))));
    const int k = (Aa > AT[1]) + (Aa > AT[2]) + (Aa > AT[3])
                + (Aa > AT[4]) + (Aa > AT[5]);
    return (k << 6) | (cyi << 3) | cxi;
}

// ---- kA: per-(bucket,batch) candidate lists straight from raw gt_boxes ----
// Record pos carries: listLo {g0, g1, g2+1, g3+1}, listA area, listHi {cls,g2,g3}.
// Compaction preserves ascending gt order -> first-max tie-break intact.
__global__ __launch_bounds__(64) void kA_lists(
    const float* __restrict__ gt, const float* __restrict__ im_info,
    float4* __restrict__ listLo, float* __restrict__ listA,
    float4* __restrict__ listHi, int* __restrict__ cnt_arr,
    double* __restrict__ ws, int G, int B)
{
#pragma clang fp contract(off)
    const int bk = blockIdx.x, b = blockIdx.y, lane = threadIdx.x;
    if (bk == 0 && b == 0 && lane < 50) ws[lane] = 0.0;  // accumulators + done ctr

    const int nv = __builtin_amdgcn_readfirstlane((int)im_info[b * 6 + 5]);
    const int cxi = bk & 7, cyi = (bk >> 3) & 7, k = bk >> 6;
    const float cx0 = cxi * 128.f, cx1 = cx0 + 128.f;
    const float cy0 = cyi * 128.f, cy1 = cy0 + 128.f;
    const float Alo = AT[k], Ahi = AT[k + 1];
    const size_t li = (size_t)(b * NB + bk) * G;

    int cnt = 0;
    for (int base = 0; base < nv; base += 64) {
        const int j = base + lane;
        bool keep = false;
        float g0 = 0.f, g1 = 0.f, g2 = 0.f, g3 = 0.f, cls = 0.f, area = 0.f;
        float g2p = 0.f, g3p = 0.f;
        if (j < nv) {
            const float* s = gt + ((size_t)b * G + j) * 5;
            g0 = s[0]; g1 = s[1]; g2 = s[2]; g3 = s[3]; cls = s[4];
            area = (g2 - g0 + 1.f) * (g3 - g1 + 1.f);   // exact ref op order
            g2p = g2 + 1.f; g3p = g3 + 1.f;             // pre-added +1
            const float wg = g2p - g0;                  // same as validated R12
            const float hg = g3p - g1;
            const float ox = fminf(cx1 + 129.f, g2p) - fmaxf(cx0 - 128.f, g0);
            const float oy = fminf(cy1 + 129.f, g3p) - fmaxf(cy0 - 128.f, g1);
            keep = (ox >= KEEP_T * wg) && (oy >= KEEP_T * hg)
                && (area >= KEEP_T * Alo) && (KEEP_T * area <= Ahi);
        }
        const unsigned long long m = __ballot(keep);
        if (keep) {
            const int pos = cnt + __popcll(m & ((1ull << lane) - 1ull));
            listLo[li + pos] = make_float4(g0, g1, g2p, g3p);
            listA[li + pos] = area;
            listHi[li + pos] = make_float4(cls, g2, g3, 0.f);
        }
        cnt += __popcll(m);
    }
    if (lane == 0) cnt_arr[b * NB + bk] = cnt;
}

// ---- kB: loss. Inline bucket per anchor (no sort); per-lane list walk;
//          fused last-block finalize. Numerics verbatim from validated R12. --
__global__ __launch_bounds__(256) void kB_loss(
    const float* __restrict__ pred_cls, const float* __restrict__ pred_reg,
    const float* __restrict__ anchors,
    const int* __restrict__ cnt_arr,
    const float4* __restrict__ listLo, const float* __restrict__ listA,
    const float4* __restrict__ listHi,
    int A, int G, int B,
    double* __restrict__ ws, float* __restrict__ out)
{
#pragma clang fp contract(off)
    const int t = threadIdx.x;
    const int i_raw = blockIdx.x * 256 + t;
    const bool live = i_raw < A;
    const int a = min(i_raw, A - 1);

    const float4 anc = *reinterpret_cast<const float4*>(anchors + 4 * (size_t)a);
    const int bk = bucket_of(anc);
    const float a0 = anc.x, a1 = anc.y;
    const float aw = anc.z - anc.x + 1.f;
    const float ah = anc.w - anc.y + 1.f;
    const float area_a = aw * ah;
    const float a2p = anc.z + 1.f;    // +1 pre-added (commutes with min exactly)
    const float a3p = anc.w + 1.f;

    float lc = 0.f, lr = 0.f;
    int fg = 0;

    for (int b = 0; b < B; ++b) {
        const int li = b * NB + bk;
        const int cnt = cnt_arr[li];
        const float4* __restrict__ Lo = listLo + (size_t)li * G;
        const float* __restrict__ La = listA + (size_t)li * G;

        // Division-free IoU argmax over candidates (ascending gt order in
        // list -> first-max preserved; pruned gts provably < 0.37 iou).
        float bi = -1.f, bS = 1.f;
        int argp = 0;
        for (int g = 0; g < cnt; ++g) {
            const float4 q = Lo[g];
            const float sg = La[g];
            const float iw = fminf(a2p, q.z) - fmaxf(a0, q.x);
            const float ih = fminf(a3p, q.w) - fmaxf(a1, q.y);
            const float inter = fmaxf(iw, 0.f) * fmaxf(ih, 0.f);
            const float S = area_a + sg;
            const bool upd = inter * bS > bi * S;
            bi   = upd ? inter : bi;
            bS   = upd ? S     : bS;
            argp = upd ? g     : argp;
        }

        if (live) {
            // ONE division, exact ref expr: inter/((area_a+area_g)-inter).
            // cnt==0 -> max_ov=-0.5 -> bg (correct: all pruned ious < 0.37).
            const float max_ov = bi / (bS - bi);

            float label = 0.f;
            bool valid = true;
            float4 hi = make_float4(0.f, 0.f, 0.f, 0.f);
            if (max_ov >= POS_T) {
                hi = listHi[(size_t)li * G + argp];
                label = hi.x;
            } else if (max_ov >= NEG_T) {
                valid = false;                 // ignore band
            }
            const int f = (label > 0.f) ? 1 : 0;
            fg += f;

            if (valid) {
                const float x = pred_cls[(size_t)b * A + a];
                const float p = 1.f / (1.f + expf(-x));
                const float l1p = log1pf(expf(-fabsf(x)));
                const float log_p  = fminf(x, 0.f) - l1p;    // log_sigmoid(x)
                const float log_np = fminf(-x, 0.f) - l1p;   // log_sigmoid(-x)
                const float pos = (label == 1.f) ? 1.f : 0.f;
                const float omp = 1.f - p;
                lc += -(F_ALPHA * pos * (omp * omp) * log_p
                        + (1.f - F_ALPHA) * (1.f - pos) * (p * p) * log_np);
            }

            if (f) {
                const float4 lo = Lo[argp];          // {g0, g1, g2+1, g3+1}
                const float g0 = lo.x, g1 = lo.y;
                const float g2 = hi.y, g3 = hi.z;    // originals
                const float gw = g2 - g0 + 1.f;
                const float gh = g3 - g1 + 1.f;
                const float gx = g0 + 0.5f * gw;
                const float gy = g1 + 0.5f * gh;
                const float axc = a0 + 0.5f * aw;
                const float ayc = a1 + 0.5f * ah;
                const float t0 = (gx - axc) / aw;
                const float t1 = (gy - ayc) / ah;
                const float t2 = logf(gw / aw);
                const float t3 = logf(gh / ah);
                const float4 rr = *reinterpret_cast<const float4*>(
                    pred_reg + 4 * ((size_t)b * A + a));
                lr += smooth_l1(rr.x - t0) + smooth_l1(rr.y - t1)
                    + smooth_l1(rr.z - t2) + smooth_l1(rr.w - t3);
            }
        }
    }

    // wave64 reduction
    for (int off = 32; off > 0; off >>= 1) {
        lc += __shfl_down(lc, off);
        lr += __shfl_down(lr, off);
        fg += __shfl_down(fg, off);
    }

    __shared__ float s_lc[4], s_lr[4];
    __shared__ int s_np[4];
    const int wid = t >> 6;
    const int lane = t & 63;
    if (lane == 0) { s_lc[wid] = lc; s_lr[wid] = lr; s_np[wid] = fg; }
    __syncthreads();
    if (t == 0) {
        const float tlc = s_lc[0] + s_lc[1] + s_lc[2] + s_lc[3];
        const float tlr = s_lr[0] + s_lr[1] + s_lr[2] + s_lr[3];
        const int   tnp = s_np[0] + s_np[1] + s_np[2] + s_np[3];
        __hip_atomic_fetch_add(&ws[0],  (double)tlc, __ATOMIC_RELAXED, __HIP_MEMORY_SCOPE_AGENT);
        __hip_atomic_fetch_add(&ws[16], (double)tlr, __ATOMIC_RELAXED, __HIP_MEMORY_SCOPE_AGENT);
        __hip_atomic_fetch_add(&ws[32], (double)tnp, __ATOMIC_RELAXED, __HIP_MEMORY_SCOPE_AGENT);

        // Fused finalize: last block to arrive computes the output.
        __threadfence();                       // device-scope release
        int* done = (int*)(ws + 48);           // byte 384, zeroed by kA
        const int prev = __hip_atomic_fetch_add(done, 1, __ATOMIC_ACQ_REL,
                                                __HIP_MEMORY_SCOPE_AGENT);
        if (prev == (int)gridDim.x - 1) {
            __threadfence();
            const double cls_s = __hip_atomic_load(&ws[0],  __ATOMIC_ACQUIRE, __HIP_MEMORY_SCOPE_AGENT);
            const double reg_s = __hip_atomic_load(&ws[16], __ATOMIC_ACQUIRE, __HIP_MEMORY_SCOPE_AGENT);
            const double np_s  = __hip_atomic_load(&ws[32], __ATOMIC_ACQUIRE, __HIP_MEMORY_SCOPE_AGENT);
            const double npos = np_s < 1.0 ? 1.0 : np_s;
            const double norm = 0.9 * 100.0 + 0.1 * npos;
            out[0] = (float)(cls_s / norm);
            out[1] = (float)(reg_s / norm);
        }
    }
}

extern "C" void kernel_launch(void* const* d_in, const int* in_sizes, int n_in,
                              void* d_out, int out_size, void* d_ws, size_t ws_size,
                              hipStream_t stream) {
    const float* pred_cls = (const float*)d_in[0];
    const float* pred_reg = (const float*)d_in[1];
    const float* anchors  = (const float*)d_in[2];
    const float* gt_boxes = (const float*)d_in[3];
    const float* im_info  = (const float*)d_in[4];

    const int A = in_sizes[2] / 4;
    const int B = in_sizes[4] / 6;
    const int G = in_sizes[3] / (B * 5);

    // ---- ws layout ----
    char* base = (char*)d_ws;
    double* ws = (double*)base;                  // [0,512): accumulators + done ctr
    size_t off = 512;
    float4* listLo = (float4*)(base + off);  off += (size_t)B * NB * G * 16;
    float*  listA  = (float*)(base + off);   off += (size_t)B * NB * G * 4;
    off = (off + 255) & ~(size_t)255;
    float4* listHi = (float4*)(base + off);  off += (size_t)B * NB * G * 16;
    off = (off + 255) & ~(size_t)255;
    int* cnt_arr = (int*)(base + off);       off += (size_t)B * NB * 4;

    kA_lists<<<dim3(NB, B), 64, 0, stream>>>(
        gt_boxes, im_info, listLo, listA, listHi, cnt_arr, ws, G, B);

    const int CH = (A + 255) / 256;
    kB_loss<<<CH, 256, 0, stream>>>(
        pred_cls, pred_reg, anchors, cnt_arr, listLo, listA, listHi,
        A, G, B, ws, (float*)d_out);
}

// Round 15
// 78.374 us; speedup vs baseline: 5.4525x; 1.1752x over previous
//
#include <hip/hip_runtime.h>
#include <math.h>

// CrowdDet RetinaNet loss constants
#define POS_T 0.5f
#define NEG_T 0.4f
#define F_ALPHA 0.25f
#define SL1_BETA 0.1f
#define SENT 3.0e8f

// Pruning geometry (validated R10-R14): 8x8 cells of 128px, 6 area classes.
#define NCELL 8
#define NCLASS 6
#define NB (NCELL * NCELL * NCLASS)   // 384 buckets
#define KEEP_T 0.37f
#define APT 8                          // anchors per thread in k1/k3

typedef __attribute__((ext_vector_type(8))) int i8x;

// Anchor legacy-area class thresholds: 289 * 2.5^k (exact in f32).
__device__ __constant__ float AT[7] = {
    289.f, 722.5f, 1806.25f, 4515.625f, 11289.0625f, 28222.65625f, 70556.640625f};

__device__ __forceinline__ float smooth_l1(float d) {
    d = fabsf(d);
    return d < SL1_BETA ? 0.5f * d * d / SL1_BETA : d - SL1_BETA;
}

__device__ __forceinline__ int bucket_of(const float4 av) {
    const float aw = av.z - av.x + 1.f, ah = av.w - av.y + 1.f;
    const float Aa = aw * ah;
    const float cx = 0.5f * (av.x + av.z);
    const float cy = 0.5f * (av.y + av.w);
    const int cxi = min(NCELL - 1, max(0, (int)(cx * (1.0f / 128.f))));
    const int cyi = min(NCELL - 1, max(0, (int)(cy * (1.0f / 128.f))));
    const int k = (Aa > AT[1]) + (Aa > AT[2]) + (Aa > AT[3])
                + (Aa > AT[4]) + (Aa > AT[5]);
    return (k << 6) | (cyi << 3) | cxi;
}

// ---- K1: anchor buckets + per-block LDS hist; prefill sortedA/wavebkt/ws ---
__global__ __launch_bounds__(256) void k1_assign(
    const float* __restrict__ anchors,
    int* __restrict__ bucketid, int* __restrict__ blockhist, // [nablk][NB]
    int* __restrict__ sortedA, int* __restrict__ wavebkt,
    double* __restrict__ ws,
    int A, int PADTOT, int NWMAX, int nablk)
{
#pragma clang fp contract(off)
    __shared__ int lh[NB];
    const int t = threadIdx.x;
    for (int i = t; i < NB; i += 256) lh[i] = 0;
    __syncthreads();

    const int gid = blockIdx.x * 256 + t;
    if (gid < 50) ws[gid] = 0.0;                 // accumulators + done ctr
    const int stride = nablk * 256;
    for (int j = gid; j < PADTOT; j += stride) sortedA[j] = -1;
    for (int j = gid; j < NWMAX; j += stride) wavebkt[j] = -1;

    const int abase = gid * APT;
    #pragma unroll
    for (int u = 0; u < APT; ++u) {
        const int ai = abase + u;
        if (ai < A) {
            const float4 av = *reinterpret_cast<const float4*>(anchors + 4 * (size_t)ai);
            const int bk = bucket_of(av);
            bucketid[ai] = bk;
            atomicAdd(&lh[bk], 1);               // LDS atomic, cheap
        }
    }
    __syncthreads();
    for (int j = t; j < NB; j += 256)
        blockhist[(size_t)blockIdx.x * NB + j] = lh[j];
}

// ---- K2: per-bucket scan of block hists + SoA candidate lists --------------
// SoA chunk = {G0[8],G1[8],G2P[8],G3P[8],AREA[8]} (5x s_load_dwordx8 in k4).
// Tail sentinel-padded to chunk multiple (sentinel can't win argmax once a
// real gt is in; lists keep ascending gt order -> first-max preserved).
__global__ __launch_bounds__(256) void k2_scan_lists(
    int* __restrict__ bh, int* __restrict__ totals,
    const float* __restrict__ gt, const float* __restrict__ im_info,
    int* __restrict__ cnt_arr, float* __restrict__ soa,
    float4* __restrict__ eLo, float* __restrict__ eCls,
    int nablk, int G, int NCH, int B)
{
#pragma clang fp contract(off)
    const int bk = blockIdx.x, t = threadIdx.x;

    // Phase 1: exclusive scan of bh[blk][bk] over blk (nablk <= 256).
    __shared__ int s[256];
    const int v = (t < nablk) ? bh[(size_t)t * NB + bk] : 0;
    s[t] = v;
    __syncthreads();
    for (int d = 1; d < 256; d <<= 1) {
        const int u = (t >= d) ? s[t - d] : 0;
        __syncthreads();
        s[t] += u;
        __syncthreads();
    }
    if (t < nablk) bh[(size_t)t * NB + bk] = s[t] - v;   // exclusive prefix
    if (t == 255) totals[bk] = s[255];

    // Phase 2: candidate lists, one batch per wave (validated keep-test).
    const int wid = t >> 6, lane = t & 63;
    const int cxi = bk & 7, cyi = (bk >> 3) & 7, k = bk >> 6;
    const float cx0 = cxi * 128.f, cx1 = cx0 + 128.f;
    const float cy0 = cyi * 128.f, cy1 = cy0 + 128.f;
    const float Alo = AT[k], Ahi = AT[k + 1];

    for (int b = wid; b < B; b += 4) {
        const int nv = __builtin_amdgcn_readfirstlane((int)im_info[b * 6 + 5]);
        const int li = b * NB + bk;
        float* __restrict__ sb = soa + (size_t)li * NCH * 40;
        const size_t eb = (size_t)li * G;

        int cnt = 0;
        for (int base = 0; base < nv; base += 64) {
            const int j = base + lane;
            bool keep = false;
            float g0 = 0.f, g1 = 0.f, g2 = 0.f, g3 = 0.f, cls = 0.f;
            float area = 0.f, g2p = 0.f, g3p = 0.f;
            if (j < nv) {
                const float* sp = gt + ((size_t)b * G + j) * 5;
                g0 = sp[0]; g1 = sp[1]; g2 = sp[2]; g3 = sp[3]; cls = sp[4];
                area = (g2 - g0 + 1.f) * (g3 - g1 + 1.f);   // exact ref order
                g2p = g2 + 1.f; g3p = g3 + 1.f;             // pre-added +1
                const float wg = g2p - g0;
                const float hg = g3p - g1;
                const float ox = fminf(cx1 + 129.f, g2p) - fmaxf(cx0 - 128.f, g0);
                const float oy = fminf(cy1 + 129.f, g3p) - fmaxf(cy0 - 128.f, g1);
                keep = (ox >= KEEP_T * wg) && (oy >= KEEP_T * hg)
                    && (area >= KEEP_T * Alo) && (KEEP_T * area <= Ahi);
            }
            const unsigned long long m = __ballot(keep);
            if (keep) {
                const int pos = cnt + __popcll(m & ((1ull << lane) - 1ull));
                float* c = sb + (size_t)(pos >> 3) * 40 + (pos & 7);
                c[0] = g0; c[8] = g1; c[16] = g2p; c[24] = g3p; c[32] = area;
                eLo[eb + pos] = make_float4(g0, g1, g2, g3);
                eCls[eb + pos] = cls;
            }
            cnt += __popcll(m);
        }
        // Sentinel-pad the last chunk.
        const int tail = cnt & 7;
        if (tail && lane < 8 - tail) {
            const int pos = cnt + lane;
            float* c = sb + (size_t)(pos >> 3) * 40 + (pos & 7);
            c[0] = SENT; c[8] = SENT; c[16] = SENT + 2.f; c[24] = SENT + 2.f;
            c[32] = 4.f;
        }
        if (lane == 0) cnt_arr[li] = cnt;
    }
}

// ---- K3: padded bases + wave->bucket table + place anchors -----------------
__global__ __launch_bounds__(256) void k3_place(
    const int* __restrict__ bucketid, const int* __restrict__ bh,
    const int* __restrict__ totals,
    int* __restrict__ sortedA, int* __restrict__ wavebkt, int A)
{
    __shared__ int lh[NB];
    __shared__ int sbase[NB];
    const int t = threadIdx.x, blk = blockIdx.x;
    for (int i = t; i < NB; i += 256) lh[i] = 0;
    if (t < 64) {
        int carry = 0;
        #pragma unroll
        for (int r = 0; r < NB / 64; ++r) {
            int v = ((totals[r * 64 + t] + 63) >> 6) << 6;   // padded count
            const int orig = v;
            for (int d = 1; d < 64; d <<= 1) {
                const int u = __shfl_up(v, d);
                if (t >= d) v += u;
            }
            sbase[r * 64 + t] = carry + v - orig;   // exclusive padded base
            carry += __shfl(v, 63);
        }
    }
    __syncthreads();

    if (blk == 0) {        // wave->bucket table (total entries ~ A/64 + NB)
        for (int bk = t; bk < NB; bk += 256) {
            const int nw = (totals[bk] + 63) >> 6;
            const int wb = sbase[bk] >> 6;
            for (int w = 0; w < nw; ++w) wavebkt[wb + w] = bk;
        }
    }

    const int abase = (blk * 256 + t) * APT;
    #pragma unroll
    for (int u = 0; u < APT; ++u) {
        const int ai = abase + u;
        if (ai < A) {
            const int bk = bucketid[ai];
            const int lrk = atomicAdd(&lh[bk], 1);
            sortedA[sbase[bk] + bh[(size_t)blk * NB + bk] + lrk] = ai;
        }
    }
}

// ---- K4: main loss. Wave-uniform bucket; SGPR chunk fetch (R7-validated
//          s_load asm); both batches per thread; fused last-block finalize. --
__global__ __launch_bounds__(256) void k4_loss(
    const float* __restrict__ pred_cls, const float* __restrict__ pred_reg,
    const float* __restrict__ anchors,
    const int* __restrict__ sortedA, const int* __restrict__ wavebkt,
    const int* __restrict__ cnt_arr, const float* __restrict__ soa,
    const float4* __restrict__ eLo, const float* __restrict__ eCls,
    int A, int G, int NCH, int B,
    double* __restrict__ ws, float* __restrict__ out)
{
#pragma clang fp contract(off)
    const int t = threadIdx.x;
    const int lane = t & 63;
    const int wgid = __builtin_amdgcn_readfirstlane(blockIdx.x * 4 + (t >> 6));
    const int bk = __builtin_amdgcn_readfirstlane(wavebkt[wgid]);

    float lc = 0.f, lr = 0.f;
    int fg = 0;

    if (bk >= 0) {
        const int ai = sortedA[wgid * 64 + lane];
        const bool live = ai >= 0;
        const int a = max(ai, 0);

        const float4 anc = *reinterpret_cast<const float4*>(anchors + 4 * (size_t)a);
        const float a0 = anc.x, a1 = anc.y;
        const float aw = anc.z - anc.x + 1.f;
        const float ah = anc.w - anc.y + 1.f;
        const float area_a = aw * ah;
        const float a2p = anc.z + 1.f;    // +1 pre-added (commutes with min)
        const float a3p = anc.w + 1.f;

        for (int b = 0; b < B; ++b) {
            const int li = b * NB + bk;
            const int cnt = __builtin_amdgcn_readfirstlane(cnt_arr[li]);
            const int nch = (cnt + 7) >> 3;
            const float* lbase = soa + (size_t)li * NCH * 40;

            // Division-free IoU argmax (validated): strict > == first-max;
            // sentinels (inter=0) can't win once a real gt (bi>=0) is in.
            float bi = -1.f, bS = 1.f;
            int argp = 0;
            for (int c = 0; c < nch; ++c) {
                const float* cp = lbase + (size_t)c * 40;
                i8x r0, r1, r2, r3, r4;
                asm volatile(
                    "s_load_dwordx8 %0, %5, 0x0\n\t"
                    "s_load_dwordx8 %1, %5, 0x20\n\t"
                    "s_load_dwordx8 %2, %5, 0x40\n\t"
                    "s_load_dwordx8 %3, %5, 0x60\n\t"
                    "s_load_dwordx8 %4, %5, 0x80\n\t"
                    "s_waitcnt lgkmcnt(0)"
                    : "=s"(r0), "=s"(r1), "=s"(r2), "=s"(r3), "=s"(r4)
                    : "s"(cp));
                const int cb = c << 3;
                #pragma unroll
                for (int j = 0; j < 8; ++j) {
                    const float g0  = __int_as_float(r0[j]);
                    const float g1  = __int_as_float(r1[j]);
                    const float g2p = __int_as_float(r2[j]);
                    const float g3p = __int_as_float(r3[j]);
                    const float sg  = __int_as_float(r4[j]);
                    const float iw = fminf(a2p, g2p) - fmaxf(a0, g0);
                    const float ih = fminf(a3p, g3p) - fmaxf(a1, g1);
                    const float inter = fmaxf(iw, 0.f) * fmaxf(ih, 0.f);
                    const float S = area_a + sg;
                    const bool upd = inter * bS > bi * S;
                    bi   = upd ? inter    : bi;
                    bS   = upd ? S        : bS;
                    argp = upd ? (cb + j) : argp;
                }
            }

            if (live) {
                // ONE division, exact ref expr: inter/((area_a+area_g)-inter).
                // cnt==0 -> max_ov=-0.5 -> bg (validated: pruned ious < 0.37).
                const float max_ov = bi / (bS - bi);

                float label = 0.f;
                bool valid = true;
                if (max_ov >= POS_T) {
                    label = eCls[(size_t)li * G + argp];
                } else if (max_ov >= NEG_T) {
                    valid = false;                 // ignore band
                }
                const int f = (label > 0.f) ? 1 : 0;
                fg += f;

                if (valid) {
                    const float x = pred_cls[(size_t)b * A + a];
                    const float p = 1.f / (1.f + expf(-x));
                    const float l1p = log1pf(expf(-fabsf(x)));
                    const float log_p  = fminf(x, 0.f) - l1p;    // log_sigmoid(x)
                    const float log_np = fminf(-x, 0.f) - l1p;   // log_sigmoid(-x)
                    const float pos = (label == 1.f) ? 1.f : 0.f;
                    const float omp = 1.f - p;
                    lc += -(F_ALPHA * pos * (omp * omp) * log_p
                            + (1.f - F_ALPHA) * (1.f - pos) * (p * p) * log_np);
                }

                if (f) {
                    const float4 gb = eLo[(size_t)li * G + argp];  // originals
                    const float gw = gb.z - gb.x + 1.f;
                    const float gh = gb.w - gb.y + 1.f;
                    const float gx = gb.x + 0.5f * gw;
                    const float gy = gb.y + 0.5f * gh;
                    const float axc = a0 + 0.5f * aw;
                    const float ayc = a1 + 0.5f * ah;
                    const float t0 = (gx - axc) / aw;
                    const float t1 = (gy - ayc) / ah;
                    const float t2 = logf(gw / aw);
                    const float t3 = logf(gh / ah);
                    const float4 rr = *reinterpret_cast<const float4*>(
                        pred_reg + 4 * ((size_t)b * A + a));
                    lr += smooth_l1(rr.x - t0) + smooth_l1(rr.y - t1)
                        + smooth_l1(rr.z - t2) + smooth_l1(rr.w - t3);
                }
            }
        }
    }

    // wave64 reduction + block atomics + fused last-block finalize (R14-valid).
    for (int off = 32; off > 0; off >>= 1) {
        lc += __shfl_down(lc, off);
        lr += __shfl_down(lr, off);
        fg += __shfl_down(fg, off);
    }
    __shared__ float s_lc[4], s_lr[4];
    __shared__ int s_np[4];
    const int wid = t >> 6;
    if (lane == 0) { s_lc[wid] = lc; s_lr[wid] = lr; s_np[wid] = fg; }
    __syncthreads();
    if (t == 0) {
        const float tlc = s_lc[0] + s_lc[1] + s_lc[2] + s_lc[3];
        const float tlr = s_lr[0] + s_lr[1] + s_lr[2] + s_lr[3];
        const int   tnp = s_np[0] + s_np[1] + s_np[2] + s_np[3];
        __hip_atomic_fetch_add(&ws[0],  (double)tlc, __ATOMIC_RELAXED, __HIP_MEMORY_SCOPE_AGENT);
        __hip_atomic_fetch_add(&ws[16], (double)tlr, __ATOMIC_RELAXED, __HIP_MEMORY_SCOPE_AGENT);
        __hip_atomic_fetch_add(&ws[32], (double)tnp, __ATOMIC_RELAXED, __HIP_MEMORY_SCOPE_AGENT);
        __threadfence();
        int* done = (int*)(ws + 48);
        const int prev = __hip_atomic_fetch_add(done, 1, __ATOMIC_ACQ_REL,
                                                __HIP_MEMORY_SCOPE_AGENT);
        if (prev == (int)gridDim.x - 1) {
            __threadfence();
            const double cls_s = __hip_atomic_load(&ws[0],  __ATOMIC_ACQUIRE, __HIP_MEMORY_SCOPE_AGENT);
            const double reg_s = __hip_atomic_load(&ws[16], __ATOMIC_ACQUIRE, __HIP_MEMORY_SCOPE_AGENT);
            const double np_s  = __hip_atomic_load(&ws[32], __ATOMIC_ACQUIRE, __HIP_MEMORY_SCOPE_AGENT);
            const double npos = np_s < 1.0 ? 1.0 : np_s;
            const double norm = 0.9 * 100.0 + 0.1 * npos;
            out[0] = (float)(cls_s / norm);
            out[1] = (float)(reg_s / norm);
        }
    }
}

extern "C" void kernel_launch(void* const* d_in, const int* in_sizes, int n_in,
                              void* d_out, int out_size, void* d_ws, size_t ws_size,
                              hipStream_t stream) {
    const float* pred_cls = (const float*)d_in[0];
    const float* pred_reg = (const float*)d_in[1];
    const float* anchors  = (const float*)d_in[2];
    const float* gt_boxes = (const float*)d_in[3];
    const float* im_info  = (const float*)d_in[4];

    const int A = in_sizes[2] / 4;
    const int B = in_sizes[4] / 6;
    const int G = in_sizes[3] / (B * 5);
    const int NCH = (G + 7) / 8;                 // chunks per list (ceil)
    const int nablk = ((A + APT - 1) / APT + 255) / 256;   // <= 256 required
    const int PADTOT = A + NB * 64;              // padded sorted-slot bound
    const int NWMAX = (A + 63) / 64 + NB;        // wave-table bound
    const int K4B = (NWMAX + 3) / 4;             // 4 waves per block

    // ---- ws layout ----
    char* base = (char*)d_ws;
    double* ws = (double*)base;                  // [0,512): accum + done ctr
    size_t off = 512;
    float* soa = (float*)(base + off);       off += (size_t)B * NB * NCH * 40 * 4;
    off = (off + 255) & ~(size_t)255;
    float4* eLo = (float4*)(base + off);     off += (size_t)B * NB * G * 16;
    float* eCls = (float*)(base + off);      off += (size_t)B * NB * G * 4;
    off = (off + 255) & ~(size_t)255;
    int* cnt_arr = (int*)(base + off);       off += (size_t)B * NB * 4;
    int* bucketid = (int*)(base + off);      off += (size_t)A * 4;
    int* sortedA = (int*)(base + off);       off += (size_t)PADTOT * 4;
    int* wavebkt = (int*)(base + off);       off += (size_t)(NWMAX + 4) * 4;
    off = (off + 255) & ~(size_t)255;
    int* blockhist = (int*)(base + off);     off += (size_t)nablk * NB * 4;
    int* totals = (int*)(base + off);        off += (size_t)NB * 4;

    k1_assign<<<nablk, 256, 0, stream>>>(anchors, bucketid, blockhist,
                                         sortedA, wavebkt, ws,
                                         A, PADTOT, NWMAX, nablk);
    k2_scan_lists<<<NB, 256, 0, stream>>>(blockhist, totals, gt_boxes, im_info,
                                          cnt_arr, soa, eLo, eCls,
                                          nablk, G, NCH, B);
    k3_place<<<nablk, 256, 0, stream>>>(bucketid, blockhist, totals,
                                        sortedA, wavebkt, A);
    k4_loss<<<K4B, 256, 0, stream>>>(pred_cls, pred_reg, anchors,
                                     sortedA, wavebkt, cnt_arr, soa, eLo, eCls,
                                     A, G, NCH, B, ws, (float*)d_out);
}